// Round 1
// baseline (283.810 us; speedup 1.0000x reference)
//
#include <hip/hip_runtime.h>
#include <hip/hip_bf16.h>
#include <math.h>

// Sizes for COLoRALinear: B=4, S=2048, D_IN=D_OUT=2048, E=8, R=8, SCALING=2.0
#define BATCH 4
#define SEQ   2048
#define DIN   2048
#define DOUT  2048
#define NEXP  8
#define RANK  8
#define MTOT  (BATCH * SEQ)       // 8192
#define KAUG  96                  // 64 expert + 8 shared + 24 zero pad

typedef __bf16 bf16x8 __attribute__((ext_vector_type(8)));
typedef __bf16 bf16x2 __attribute__((ext_vector_type(2)));
typedef float  f32x4  __attribute__((ext_vector_type(4)));

#define GLOBAL_AS __attribute__((address_space(1)))
#define LDS_AS    __attribute__((address_space(3)))

// ---------------------------------------------------------------------------
// K1: fused column-mean partials + fp32 -> bf16 cast of x.
// grid (4 d-chunks, 32 s-chunks, 4 batches), 256 threads; thread handles 2 cols.
// ---------------------------------------------------------------------------
__global__ __launch_bounds__(256) void mean_cast(
    const float* __restrict__ x, __bf16* __restrict__ xb, float* __restrict__ partial)
{
    const int t  = threadIdx.x;
    const int dc = blockIdx.x;   // 0..3  (512 cols each)
    const int sc = blockIdx.y;   // 0..31 (64 rows each)
    const int b  = blockIdx.z;   // 0..3
    const int i  = dc * 512 + t * 2;
    size_t base = ((size_t)b * SEQ + (size_t)sc * 64) * DIN + i;
    float a0 = 0.f, a1 = 0.f;
    for (int s = 0; s < 64; ++s) {
        const float2 v = *(const float2*)&x[base + (size_t)s * DIN];
        a0 += v.x; a1 += v.y;
        bf16x2 hv = { (__bf16)v.x, (__bf16)v.y };
        *(bf16x2*)&xb[base + (size_t)s * DIN] = hv;
    }
    float2 p = { a0, a1 };
    *(float2*)&partial[((size_t)b * 32 + sc) * DIN + i] = p;
}

// ---------------------------------------------------------------------------
// K2: reduce partials -> x_mean, logits = x_mean @ task_emb^T, softmax -> routing
// grid 4 (one block per batch), 256 threads.
// ---------------------------------------------------------------------------
__global__ __launch_bounds__(256) void routing_k(
    const float* __restrict__ partial, const float* __restrict__ task_emb,
    float* __restrict__ routing)
{
    const int b = blockIdx.x;
    const int t = threadIdx.x;
    float le[NEXP] = {0.f,0.f,0.f,0.f,0.f,0.f,0.f,0.f};
    for (int j = 0; j < DIN / 256; ++j) {
        int i = t + j * 256;
        float s = 0.f;
        for (int sc = 0; sc < 32; ++sc)
            s += partial[((size_t)b * 32 + sc) * DIN + i];
        float xm = s * (1.0f / (float)SEQ);
        #pragma unroll
        for (int e = 0; e < NEXP; ++e)
            le[e] += xm * task_emb[(size_t)e * DIN + i];
    }
    __shared__ float red[256];
    __shared__ float logits[NEXP];
    for (int e = 0; e < NEXP; ++e) {
        red[t] = le[e];
        __syncthreads();
        for (int s = 128; s > 0; s >>= 1) {
            if (t < s) red[t] += red[t + s];
            __syncthreads();
        }
        if (t == 0) logits[e] = red[0];
        __syncthreads();
    }
    if (t == 0) {
        float mx = logits[0];
        for (int e = 1; e < NEXP; ++e) mx = fmaxf(mx, logits[e]);
        float ex[NEXP], den = 0.f;
        for (int e = 0; e < NEXP; ++e) { ex[e] = expf(logits[e] - mx); den += ex[e]; }
        for (int e = 0; e < NEXP; ++e) routing[b * NEXP + e] = ex[e] / den;
    }
}

// ---------------------------------------------------------------------------
// K3a: C_aug[b][o][k] bf16: k<64 -> (1-cw)*2*routing[b][e]*expert_B[e][o][r]
//                           64..71 -> cw*2*shared_B[o][k-64]; 72..95 -> 0
// ---------------------------------------------------------------------------
__global__ __launch_bounds__(256) void build_caug(
    const float* __restrict__ expert_B, const float* __restrict__ shared_B,
    const float* __restrict__ routing, const float* __restrict__ collab,
    __bf16* __restrict__ caug)
{
    int idx = blockIdx.x * 256 + threadIdx.x;   // exactly 4*2048*96 = 786432
    int k = idx % KAUG;
    int rest = idx / KAUG;
    int o = rest % DOUT;
    int b = rest / DOUT;
    float cw = 1.0f / (1.0f + expf(-collab[0]));
    float v = 0.f;
    if (k < 64) {
        int e = k >> 3, r = k & 7;
        v = (1.0f - cw) * 2.0f * routing[b * NEXP + e]
            * expert_B[((size_t)e * DOUT + o) * RANK + r];
    } else if (k < 72) {
        v = cw * 2.0f * shared_B[(size_t)o * RANK + (k - 64)];
    }
    caug[idx] = (__bf16)v;
}

// ---------------------------------------------------------------------------
// K3b: A_augT[i][k] bf16: k<64 -> expert_A[k][i]; 64..71 -> shared_A[k-64][i]; pad 0
// ---------------------------------------------------------------------------
__global__ __launch_bounds__(256) void build_augT(
    const float* __restrict__ expert_A, const float* __restrict__ shared_A,
    __bf16* __restrict__ augT)
{
    int idx = blockIdx.x * 256 + threadIdx.x;   // exactly 2048*96 = 196608
    int k = idx % KAUG;
    int i = idx / KAUG;
    float v = 0.f;
    if (k < 64)      v = expert_A[(size_t)k * DIN + i];
    else if (k < 72) v = shared_A[(size_t)(k - 64) * DIN + i];
    augT[idx] = (__bf16)v;
}

// ---------------------------------------------------------------------------
// K4: W_eff[b] = base_W + C_aug[b] @ A_aug   (M=2048 o, N=2048 i, K=96)
// m97-style 128x128 tile, 256 threads (4 waves), mfma_f32_16x16x32_bf16.
// grid (16 i-tiles, 16 o-tiles, 4 batches)
// ---------------------------------------------------------------------------
__global__ __launch_bounds__(256) void gemm_weff(
    const __bf16* __restrict__ caug,   // [4][2048][96]
    const __bf16* __restrict__ augT,   // [2048][96]
    const float*  __restrict__ W,      // [2048][2048]
    __bf16* __restrict__ weff)         // [4][2048][2048]
{
    __shared__ __bf16 lsA[128 * 32];
    __shared__ __bf16 lsB[128 * 32];
    const int t = threadIdx.x;
    const int lane = t & 63;
    const int wm = (t >> 6) >> 1, wn = (t >> 6) & 1;
    const int b  = blockIdx.z;
    const int o0 = blockIdx.y * 128;
    const int i0 = blockIdx.x * 128;
    const __bf16* ca = caug + (size_t)b * DOUT * KAUG;

    f32x4 acc[4][4];
    #pragma unroll
    for (int a = 0; a < 4; ++a)
        #pragma unroll
        for (int c = 0; c < 4; ++c) acc[a][c] = (f32x4){0.f, 0.f, 0.f, 0.f};

    for (int k0 = 0; k0 < KAUG; k0 += 32) {
        #pragma unroll
        for (int q = 0; q < 2; ++q) {
            int L = q * 256 + t;
            int row = L >> 2, seg = L & 3;
            const __bf16* gpA = ca   + (size_t)(o0 + row) * KAUG + k0 + seg * 8;
            const __bf16* gpB = augT + (size_t)(i0 + row) * KAUG + k0 + seg * 8;
            int Lu = q * 256 + (t & ~63);   // wave-uniform LDS base
            __builtin_amdgcn_global_load_lds((GLOBAL_AS void*)gpA,
                (LDS_AS void*)&lsA[Lu * 8], 16, 0, 0);
            __builtin_amdgcn_global_load_lds((GLOBAL_AS void*)gpB,
                (LDS_AS void*)&lsB[Lu * 8], 16, 0, 0);
        }
        __syncthreads();
        bf16x8 af[4], bfr[4];
        #pragma unroll
        for (int tm = 0; tm < 4; ++tm)
            af[tm]  = *(const bf16x8*)&lsA[(wm * 64 + tm * 16 + (lane & 15)) * 32 + (lane >> 4) * 8];
        #pragma unroll
        for (int tn = 0; tn < 4; ++tn)
            bfr[tn] = *(const bf16x8*)&lsB[(wn * 64 + tn * 16 + (lane & 15)) * 32 + (lane >> 4) * 8];
        #pragma unroll
        for (int tm = 0; tm < 4; ++tm)
            #pragma unroll
            for (int tn = 0; tn < 4; ++tn)
                acc[tm][tn] = __builtin_amdgcn_mfma_f32_16x16x32_bf16(
                    af[tm], bfr[tn], acc[tm][tn], 0, 0, 0);
        __syncthreads();
    }
    #pragma unroll
    for (int tm = 0; tm < 4; ++tm) {
        #pragma unroll
        for (int tn = 0; tn < 4; ++tn) {
            int col = i0 + wn * 64 + tn * 16 + (lane & 15);
            #pragma unroll
            for (int v = 0; v < 4; ++v) {
                int row = o0 + wm * 64 + tm * 16 + (lane >> 4) * 4 + v;
                float wv = W[(size_t)row * DIN + col];
                weff[(size_t)b * DOUT * DIN + (size_t)row * DIN + col]
                    = (__bf16)(acc[tm][tn][v] + wv);
            }
        }
    }
}

// ---------------------------------------------------------------------------
// K5: out = x_bf16 @ W_eff[b]^T + bias   (M=8192, N=2048, K=2048)
// m97-style: 128x128 tile, BK=32, global_load_lds width 16, 4x4 frags/wave.
// grid (16 n-tiles, 64 m-tiles)
// ---------------------------------------------------------------------------
__global__ __launch_bounds__(256) void gemm_main(
    const __bf16* __restrict__ xb,     // [8192][2048]
    const __bf16* __restrict__ weff,   // [4][2048][2048]
    const float*  __restrict__ bias,   // [2048]
    float* __restrict__ out)           // [8192][2048]
{
    __shared__ __bf16 lsA[128 * 32];
    __shared__ __bf16 lsB[128 * 32];
    const int t = threadIdx.x;
    const int lane = t & 63;
    const int wm = (t >> 6) >> 1, wn = (t >> 6) & 1;
    const int mt = blockIdx.y;               // 0..63
    const int m0 = mt * 128;
    const int n0 = blockIdx.x * 128;
    const __bf16* wb = weff + (size_t)(mt >> 4) * DOUT * DIN;  // batch = mt/16

    f32x4 acc[4][4];
    #pragma unroll
    for (int a = 0; a < 4; ++a)
        #pragma unroll
        for (int c = 0; c < 4; ++c) acc[a][c] = (f32x4){0.f, 0.f, 0.f, 0.f};

    for (int k0 = 0; k0 < DIN; k0 += 32) {
        #pragma unroll
        for (int q = 0; q < 2; ++q) {
            int L = q * 256 + t;
            int row = L >> 2, seg = L & 3;
            const __bf16* gpA = xb + (size_t)(m0 + row) * DIN + k0 + seg * 8;
            const __bf16* gpB = wb + (size_t)(n0 + row) * DIN + k0 + seg * 8;
            int Lu = q * 256 + (t & ~63);
            __builtin_amdgcn_global_load_lds((GLOBAL_AS void*)gpA,
                (LDS_AS void*)&lsA[Lu * 8], 16, 0, 0);
            __builtin_amdgcn_global_load_lds((GLOBAL_AS void*)gpB,
                (LDS_AS void*)&lsB[Lu * 8], 16, 0, 0);
        }
        __syncthreads();
        bf16x8 af[4], bfr[4];
        #pragma unroll
        for (int tm = 0; tm < 4; ++tm)
            af[tm]  = *(const bf16x8*)&lsA[(wm * 64 + tm * 16 + (lane & 15)) * 32 + (lane >> 4) * 8];
        #pragma unroll
        for (int tn = 0; tn < 4; ++tn)
            bfr[tn] = *(const bf16x8*)&lsB[(wn * 64 + tn * 16 + (lane & 15)) * 32 + (lane >> 4) * 8];
        #pragma unroll
        for (int tm = 0; tm < 4; ++tm)
            #pragma unroll
            for (int tn = 0; tn < 4; ++tn)
                acc[tm][tn] = __builtin_amdgcn_mfma_f32_16x16x32_bf16(
                    af[tm], bfr[tn], acc[tm][tn], 0, 0, 0);
        __syncthreads();
    }
    #pragma unroll
    for (int tm = 0; tm < 4; ++tm) {
        #pragma unroll
        for (int tn = 0; tn < 4; ++tn) {
            int col = n0 + wn * 64 + tn * 16 + (lane & 15);
            float bv = bias[col];
            #pragma unroll
            for (int v = 0; v < 4; ++v) {
                int row = m0 + wm * 64 + tm * 16 + (lane >> 4) * 4 + v;
                out[(size_t)row * DOUT + col] = acc[tm][tn][v] + bv;
            }
        }
    }
}

// ---------------------------------------------------------------------------
// Workspace layout (bytes):
//   xb      @ 0         : 8192*2048*2      = 33,554,432
//   weff    @ 33554432  : 4*2048*2048*2    = 33,554,432
//   partial @ 67108864  : 4*32*2048*4      =  1,048,576
//   routing @ 68157440  : 4*8*4 (pad 256)
//   caug    @ 68157696  : 4*2048*96*2      =  1,572,864
//   augT    @ 69730560  : 2048*96*2        =    393,216
//   total ~ 70.1 MB
// ---------------------------------------------------------------------------
extern "C" void kernel_launch(void* const* d_in, const int* in_sizes, int n_in,
                              void* d_out, int out_size, void* d_ws, size_t ws_size,
                              hipStream_t stream)
{
    const float* x        = (const float*)d_in[0];
    const float* base_W   = (const float*)d_in[1];
    const float* base_b   = (const float*)d_in[2];
    const float* shared_A = (const float*)d_in[3];
    const float* shared_B = (const float*)d_in[4];
    const float* expert_A = (const float*)d_in[5];
    const float* expert_B = (const float*)d_in[6];
    const float* task_emb = (const float*)d_in[7];
    const float* collab_w = (const float*)d_in[8];
    float* out = (float*)d_out;

    char* ws = (char*)d_ws;
    __bf16* xb      = (__bf16*)(ws + 0);
    __bf16* weff    = (__bf16*)(ws + 33554432);
    float*  partial = (float*) (ws + 67108864);
    float*  routing = (float*) (ws + 68157440);
    __bf16* caug    = (__bf16*)(ws + 68157696);
    __bf16* augT    = (__bf16*)(ws + 69730560);

    mean_cast <<<dim3(4, 32, 4), 256, 0, stream>>>(x, xb, partial);
    routing_k <<<dim3(4), 256, 0, stream>>>(partial, task_emb, routing);
    build_caug<<<dim3((BATCH * DOUT * KAUG) / 256), 256, 0, stream>>>(
        expert_B, shared_B, routing, collab_w, caug);
    build_augT<<<dim3((DIN * KAUG) / 256), 256, 0, stream>>>(expert_A, shared_A, augT);
    gemm_weff <<<dim3(16, 16, 4), 256, 0, stream>>>(caug, augT, base_W, weff);
    gemm_main <<<dim3(16, 64), 256, 0, stream>>>(xb, weff, base_b, out);
}

// Round 2
// 277.505 us; speedup vs baseline: 1.0227x; 1.0227x over previous
//
#include <hip/hip_runtime.h>
#include <hip/hip_bf16.h>
#include <math.h>

// COLoRALinear: B=4, S=2048, D_IN=D_OUT=2048, E=8, R=8, SCALING=2.0
#define BATCH 4
#define SEQ   2048
#define DIN   2048
#define DOUT  2048
#define NEXP  8
#define RANK  8
#define MTOT  (BATCH * SEQ)   // 8192
#define KP    128             // padded low-rank K: 64 expert + 8 shared + 56 zero

typedef __bf16 bf16x8 __attribute__((ext_vector_type(8)));
typedef __bf16 bf16x4 __attribute__((ext_vector_type(4)));
typedef __bf16 bf16x2 __attribute__((ext_vector_type(2)));
typedef float  f32x4  __attribute__((ext_vector_type(4)));

#define GLOBAL_AS __attribute__((address_space(1)))
#define LDS_AS    __attribute__((address_space(3)))

// XOR swizzle: LDS[row][slot] holds global 8-elem segment (slot ^ f(row)),
// f(row) = (row>>1)&3. Reader wanting segment q reads slot q^f(row).
// Makes fragment ds_read_b128 2-way bank aliased (free, m136) instead of 4-way.
__device__ __forceinline__ int swz(int row, int s) { return s ^ ((row >> 1) & 3); }

// ---------------------------------------------------------------------------
// K1: cast x -> bf16 and atomicAdd per-column sums into x_mean[b][i].
// grid (4 col-chunks, 32 row-chunks, 4 batches) x 256 threads, 2 cols/thread.
// ---------------------------------------------------------------------------
__global__ __launch_bounds__(256) void mean_cast(
    const float* __restrict__ x, __bf16* __restrict__ xb, float* __restrict__ x_mean)
{
    const int t  = threadIdx.x;
    const int dc = blockIdx.x;
    const int sc = blockIdx.y;
    const int b  = blockIdx.z;
    const int i  = dc * 512 + t * 2;
    size_t base = ((size_t)b * SEQ + (size_t)sc * 64) * DIN + i;
    float a0 = 0.f, a1 = 0.f;
    for (int s = 0; s < 64; ++s) {
        const float2 v = *(const float2*)&x[base + (size_t)s * DIN];
        a0 += v.x; a1 += v.y;
        bf16x2 hv = { (__bf16)v.x, (__bf16)v.y };
        *(bf16x2*)&xb[base + (size_t)s * DIN] = hv;
    }
    atomicAdd(&x_mean[(size_t)b * DIN + i],     a0);
    atomicAdd(&x_mean[(size_t)b * DIN + i + 1], a1);
}

// ---------------------------------------------------------------------------
// K2: logits = (x_mean/SEQ) @ task_emb^T, softmax -> routing[4][8]. grid 4.
// ---------------------------------------------------------------------------
__global__ __launch_bounds__(256) void routing_k(
    const float* __restrict__ x_mean, const float* __restrict__ task_emb,
    float* __restrict__ routing)
{
    const int b = blockIdx.x;
    const int t = threadIdx.x;
    float le[NEXP] = {0.f,0.f,0.f,0.f,0.f,0.f,0.f,0.f};
    for (int j = 0; j < DIN / 256; ++j) {
        int i = t + j * 256;
        float xm = x_mean[(size_t)b * DIN + i] * (1.0f / (float)SEQ);
        #pragma unroll
        for (int e = 0; e < NEXP; ++e)
            le[e] += xm * task_emb[(size_t)e * DIN + i];
    }
    __shared__ float red[256];
    __shared__ float logits[NEXP];
    for (int e = 0; e < NEXP; ++e) {
        red[t] = le[e];
        __syncthreads();
        for (int s = 128; s > 0; s >>= 1) {
            if (t < s) red[t] += red[t + s];
            __syncthreads();
        }
        if (t == 0) logits[e] = red[0];
        __syncthreads();
    }
    if (t == 0) {
        float mx = logits[0];
        for (int e = 1; e < NEXP; ++e) mx = fmaxf(mx, logits[e]);
        float ex[NEXP], den = 0.f;
        for (int e = 0; e < NEXP; ++e) { ex[e] = expf(logits[e] - mx); den += ex[e]; }
        for (int e = 0; e < NEXP; ++e) routing[b * NEXP + e] = ex[e] / den;
    }
}

// ---------------------------------------------------------------------------
// K3: fused weight prep.
//   blocks [0,4096):    Wb = bf16(W), 4 elems/thread
//   blocks [4096,8192): caugp[b][o][k] (k<64: (1-cw)*2*routing[b][e]*expert_B;
//                       64..71: cw*2*shared_B; else 0), 1 elem/thread
//   blocks [8192,9216): Ab[k][i] (k<64: expert_A row k; 64..71: shared_A; else 0)
// ---------------------------------------------------------------------------
__global__ __launch_bounds__(256) void prep_k(
    const float* __restrict__ W,
    const float* __restrict__ expert_A, const float* __restrict__ shared_A,
    const float* __restrict__ expert_B, const float* __restrict__ shared_B,
    const float* __restrict__ routing, const float* __restrict__ collab,
    __bf16* __restrict__ Wb, __bf16* __restrict__ caugp, __bf16* __restrict__ Ab)
{
    const int bid = blockIdx.x;
    const int t = threadIdx.x;
    if (bid < 4096) {
        size_t idx = ((size_t)bid * 256 + t) * 4;
        float4 v = *(const float4*)&W[idx];
        bf16x4 h = { (__bf16)v.x, (__bf16)v.y, (__bf16)v.z, (__bf16)v.w };
        *(bf16x4*)&Wb[idx] = h;
    } else if (bid < 8192) {
        int idx = (bid - 4096) * 256 + t;          // 4*2048*128 = 1048576
        int k = idx & 127;
        int o = (idx >> 7) & 2047;
        int b = idx >> 18;
        float cw = 1.0f / (1.0f + expf(-collab[0]));
        float v = 0.f;
        if (k < 64) {
            int e = k >> 3, r = k & 7;
            v = (1.0f - cw) * 2.0f * routing[b * NEXP + e]
                * expert_B[((size_t)e * DOUT + o) * RANK + r];
        } else if (k < 72) {
            v = cw * 2.0f * shared_B[(size_t)o * RANK + (k - 64)];
        }
        caugp[idx] = (__bf16)v;
    } else {
        int idx = (bid - 8192) * 256 + t;          // 128*2048 = 262144
        int i = idx & 2047;
        int k = idx >> 11;
        float v = 0.f;
        if (k < 64)      v = expert_A[(size_t)k * DIN + i];
        else if (k < 72) v = shared_A[(size_t)(k - 64) * DIN + i];
        Ab[idx] = (__bf16)v;
    }
}

// ---------------------------------------------------------------------------
// K4: split-K low-rank GEMM: partial_t[kc][m][128] = xb[m][kc*512:+512] @ Ab^T
// grid (4 ksplit, 64 m-tiles), 256 threads. m97 structure, swizzled LDS.
// ---------------------------------------------------------------------------
__global__ __launch_bounds__(256) void gemm_t(
    const __bf16* __restrict__ xb, const __bf16* __restrict__ Ab,
    float* __restrict__ pt)
{
    __shared__ __bf16 lsA[128 * 32];
    __shared__ __bf16 lsB[128 * 32];
    const int t = threadIdx.x;
    const int lane = t & 63;
    const int wm = (t >> 6) >> 1, wn = (t >> 6) & 1;
    const int kc = blockIdx.x;
    const int m0 = blockIdx.y * 128;

    f32x4 acc[4][4];
    #pragma unroll
    for (int a = 0; a < 4; ++a)
        #pragma unroll
        for (int c = 0; c < 4; ++c) acc[a][c] = (f32x4){0.f, 0.f, 0.f, 0.f};

    for (int k0 = kc * 512; k0 < kc * 512 + 512; k0 += 32) {
        #pragma unroll
        for (int q = 0; q < 2; ++q) {
            int L = q * 256 + t;
            int row = L >> 2, s = L & 3;
            int seg = swz(row, s);
            const __bf16* gpA = xb + (size_t)(m0 + row) * DIN + k0 + seg * 8;
            const __bf16* gpB = Ab + (size_t)row * DIN + k0 + seg * 8;
            int Lu = q * 256 + (t & ~63);
            __builtin_amdgcn_global_load_lds((GLOBAL_AS void*)gpA,
                (LDS_AS void*)&lsA[Lu * 8], 16, 0, 0);
            __builtin_amdgcn_global_load_lds((GLOBAL_AS void*)gpB,
                (LDS_AS void*)&lsB[Lu * 8], 16, 0, 0);
        }
        __syncthreads();
        bf16x8 af[4], bfr[4];
        #pragma unroll
        for (int tm = 0; tm < 4; ++tm) {
            int r = wm * 64 + tm * 16 + (lane & 15);
            af[tm] = *(const bf16x8*)&lsA[r * 32 + swz(r, lane >> 4) * 8];
        }
        #pragma unroll
        for (int tn = 0; tn < 4; ++tn) {
            int r = wn * 64 + tn * 16 + (lane & 15);
            bfr[tn] = *(const bf16x8*)&lsB[r * 32 + swz(r, lane >> 4) * 8];
        }
        #pragma unroll
        for (int tm = 0; tm < 4; ++tm)
            #pragma unroll
            for (int tn = 0; tn < 4; ++tn)
                acc[tm][tn] = __builtin_amdgcn_mfma_f32_16x16x32_bf16(
                    af[tm], bfr[tn], acc[tm][tn], 0, 0, 0);
        __syncthreads();
    }
    #pragma unroll
    for (int tm = 0; tm < 4; ++tm)
        #pragma unroll
        for (int tn = 0; tn < 4; ++tn) {
            int col = wn * 64 + tn * 16 + (lane & 15);
            #pragma unroll
            for (int v = 0; v < 4; ++v) {
                int row = m0 + wm * 64 + tm * 16 + (lane >> 4) * 4 + v;
                pt[((size_t)kc * MTOT + row) * KP + col] = acc[tm][tn][v];
            }
        }
}

// ---------------------------------------------------------------------------
// K5: tb[m][k] = bf16(sum_kc pt[kc][m][k]); 4 elems/thread.
// ---------------------------------------------------------------------------
__global__ __launch_bounds__(256) void reduce_t(
    const float* __restrict__ pt, __bf16* __restrict__ tb)
{
    size_t idx = ((size_t)blockIdx.x * 256 + threadIdx.x) * 4;  // over 8192*128
    float4 s = *(const float4*)&pt[idx];
    #pragma unroll
    for (int kc = 1; kc < 4; ++kc) {
        float4 v = *(const float4*)&pt[(size_t)kc * MTOT * KP + idx];
        s.x += v.x; s.y += v.y; s.z += v.z; s.w += v.w;
    }
    bf16x4 h = { (__bf16)s.x, (__bf16)s.y, (__bf16)s.z, (__bf16)s.w };
    *(bf16x4*)&tb[idx] = h;
}

// ---------------------------------------------------------------------------
// K6: out = xb @ Wb^T + tb @ caugp[b]^T + bias
// 64 main K-iters (stride DIN) + 3 correction K-iters (stride KP).
// grid (16 n-tiles, 64 m-tiles), 256 threads.
// ---------------------------------------------------------------------------
__global__ __launch_bounds__(256) void gemm_main(
    const __bf16* __restrict__ xb, const __bf16* __restrict__ Wb,
    const __bf16* __restrict__ tb, const __bf16* __restrict__ caugp,
    const float* __restrict__ bias, float* __restrict__ out)
{
    __shared__ __bf16 lsA[128 * 32];
    __shared__ __bf16 lsB[128 * 32];
    const int t = threadIdx.x;
    const int lane = t & 63;
    const int wm = (t >> 6) >> 1, wn = (t >> 6) & 1;
    const int mt = blockIdx.y;
    const int m0 = mt * 128;
    const int n0 = blockIdx.x * 128;
    const __bf16* cb = caugp + (size_t)(mt >> 4) * DOUT * KP;   // batch = mt/16

    f32x4 acc[4][4];
    #pragma unroll
    for (int a = 0; a < 4; ++a)
        #pragma unroll
        for (int c = 0; c < 4; ++c) acc[a][c] = (f32x4){0.f, 0.f, 0.f, 0.f};

    // --- main: K = 2048 over (xb, Wb) ---
    for (int k0 = 0; k0 < DIN; k0 += 32) {
        #pragma unroll
        for (int q = 0; q < 2; ++q) {
            int L = q * 256 + t;
            int row = L >> 2, s = L & 3;
            int seg = swz(row, s);
            const __bf16* gpA = xb + (size_t)(m0 + row) * DIN + k0 + seg * 8;
            const __bf16* gpB = Wb + (size_t)(n0 + row) * DIN + k0 + seg * 8;
            int Lu = q * 256 + (t & ~63);
            __builtin_amdgcn_global_load_lds((GLOBAL_AS void*)gpA,
                (LDS_AS void*)&lsA[Lu * 8], 16, 0, 0);
            __builtin_amdgcn_global_load_lds((GLOBAL_AS void*)gpB,
                (LDS_AS void*)&lsB[Lu * 8], 16, 0, 0);
        }
        __syncthreads();
        bf16x8 af[4], bfr[4];
        #pragma unroll
        for (int tm = 0; tm < 4; ++tm) {
            int r = wm * 64 + tm * 16 + (lane & 15);
            af[tm] = *(const bf16x8*)&lsA[r * 32 + swz(r, lane >> 4) * 8];
        }
        #pragma unroll
        for (int tn = 0; tn < 4; ++tn) {
            int r = wn * 64 + tn * 16 + (lane & 15);
            bfr[tn] = *(const bf16x8*)&lsB[r * 32 + swz(r, lane >> 4) * 8];
        }
        #pragma unroll
        for (int tm = 0; tm < 4; ++tm)
            #pragma unroll
            for (int tn = 0; tn < 4; ++tn)
                acc[tm][tn] = __builtin_amdgcn_mfma_f32_16x16x32_bf16(
                    af[tm], bfr[tn], acc[tm][tn], 0, 0, 0);
        __syncthreads();
    }

    // --- correction: K = 96 over (tb, caugp[b]), stride KP=128 ---
    for (int kk = 0; kk < 3; ++kk) {
        int k0 = kk * 32;
        #pragma unroll
        for (int q = 0; q < 2; ++q) {
            int L = q * 256 + t;
            int row = L >> 2, s = L & 3;
            int seg = swz(row, s);
            const __bf16* gpA = tb + (size_t)(m0 + row) * KP + k0 + seg * 8;
            const __bf16* gpB = cb + (size_t)(n0 + row) * KP + k0 + seg * 8;
            int Lu = q * 256 + (t & ~63);
            __builtin_amdgcn_global_load_lds((GLOBAL_AS void*)gpA,
                (LDS_AS void*)&lsA[Lu * 8], 16, 0, 0);
            __builtin_amdgcn_global_load_lds((GLOBAL_AS void*)gpB,
                (LDS_AS void*)&lsB[Lu * 8], 16, 0, 0);
        }
        __syncthreads();
        bf16x8 af[4], bfr[4];
        #pragma unroll
        for (int tm = 0; tm < 4; ++tm) {
            int r = wm * 64 + tm * 16 + (lane & 15);
            af[tm] = *(const bf16x8*)&lsA[r * 32 + swz(r, lane >> 4) * 8];
        }
        #pragma unroll
        for (int tn = 0; tn < 4; ++tn) {
            int r = wn * 64 + tn * 16 + (lane & 15);
            bfr[tn] = *(const bf16x8*)&lsB[r * 32 + swz(r, lane >> 4) * 8];
        }
        #pragma unroll
        for (int tm = 0; tm < 4; ++tm)
            #pragma unroll
            for (int tn = 0; tn < 4; ++tn)
                acc[tm][tn] = __builtin_amdgcn_mfma_f32_16x16x32_bf16(
                    af[tm], bfr[tn], acc[tm][tn], 0, 0, 0);
        __syncthreads();
    }

    #pragma unroll
    for (int tm = 0; tm < 4; ++tm)
        #pragma unroll
        for (int tn = 0; tn < 4; ++tn) {
            int col = n0 + wn * 64 + tn * 16 + (lane & 15);
            float bv = bias[col];
            #pragma unroll
            for (int v = 0; v < 4; ++v) {
                int row = m0 + wm * 64 + tm * 16 + (lane >> 4) * 4 + v;
                out[(size_t)row * DOUT + col] = acc[tm][tn][v] + bv;
            }
        }
}

// ---------------------------------------------------------------------------
// Workspace (bytes):
//   xb      @ 0         : 33,554,432   (8192x2048 bf16)
//   Wb      @ 33554432  :  8,388,608   (2048x2048 bf16)
//   pt      @ 41943040  : 16,777,216   (4x8192x128 f32)
//   tb      @ 58720256  :  2,097,152   (8192x128 bf16)
//   caugp   @ 60817408  :  2,097,152   (4x2048x128 bf16)
//   Ab      @ 62914560  :    524,288   (128x2048 bf16)
//   x_mean  @ 63438848  :     32,768   (4x2048 f32)
//   routing @ 63471616  :        256
//   total ~ 63.5 MB
// ---------------------------------------------------------------------------
extern "C" void kernel_launch(void* const* d_in, const int* in_sizes, int n_in,
                              void* d_out, int out_size, void* d_ws, size_t ws_size,
                              hipStream_t stream)
{
    const float* x        = (const float*)d_in[0];
    const float* base_W   = (const float*)d_in[1];
    const float* base_b   = (const float*)d_in[2];
    const float* shared_A = (const float*)d_in[3];
    const float* shared_B = (const float*)d_in[4];
    const float* expert_A = (const float*)d_in[5];
    const float* expert_B = (const float*)d_in[6];
    const float* task_emb = (const float*)d_in[7];
    const float* collab_w = (const float*)d_in[8];
    float* out = (float*)d_out;

    char* ws = (char*)d_ws;
    __bf16* xb      = (__bf16*)(ws + 0);
    __bf16* Wb      = (__bf16*)(ws + 33554432);
    float*  pt      = (float*) (ws + 41943040);
    __bf16* tb      = (__bf16*)(ws + 58720256);
    __bf16* caugp   = (__bf16*)(ws + 60817408);
    __bf16* Ab      = (__bf16*)(ws + 62914560);
    float*  x_mean  = (float*) (ws + 63438848);
    float*  routing = (float*) (ws + 63471616);

    hipMemsetAsync(x_mean, 0, BATCH * DIN * sizeof(float), stream);
    mean_cast<<<dim3(4, 32, 4), 256, 0, stream>>>(x, xb, x_mean);
    routing_k<<<dim3(4), 256, 0, stream>>>(x_mean, task_emb, routing);
    prep_k   <<<dim3(9216), 256, 0, stream>>>(base_W, expert_A, shared_A,
                                              expert_B, shared_B, routing, collab_w,
                                              Wb, caugp, Ab);
    gemm_t   <<<dim3(4, 64), 256, 0, stream>>>(xb, Ab, pt);
    reduce_t <<<dim3(MTOT * KP / 1024), 256, 0, stream>>>(pt, tb);
    gemm_main<<<dim3(16, 64), 256, 0, stream>>>(xb, Wb, tb, caugp, base_b, out);
}

// Round 3
// 245.270 us; speedup vs baseline: 1.1571x; 1.1314x over previous
//
#include <hip/hip_runtime.h>
#include <hip/hip_bf16.h>
#include <math.h>

// COLoRALinear: B=4, S=2048, D_IN=D_OUT=2048, E=8, R=8, SCALING=2.0
#define BATCH 4
#define SEQ   2048
#define DIN   2048
#define DOUT  2048
#define NEXP  8
#define RANK  8
#define MTOT  (BATCH * SEQ)   // 8192
#define KP    128             // padded low-rank K: 64 expert + 8 shared + 56 zero

typedef __bf16 bf16x8 __attribute__((ext_vector_type(8)));
typedef __bf16 bf16x4 __attribute__((ext_vector_type(4)));
typedef float  f32x4  __attribute__((ext_vector_type(4)));

#define GLOBAL_AS __attribute__((address_space(1)))
#define LDS_AS    __attribute__((address_space(3)))

// ---------------------------------------------------------------------------
// K1: fused prep (one launch, 6400 blocks):
//  [0,256):        x -> xb (bf16) + column-sum atomics into x_mean
//  [256,4352):     W -> Wb (bf16)
//  [4352,5376):    caug[o][k]: k<64 -> (1-cw)*2*expert_B[e][o][r];
//                  64..71 -> cw*2*shared_B[o][k-64]; else 0   (batch-independent;
//                  routing[b][e] is applied on the activation side in K3)
//  [5376,6400):    Ab[k][i]: k<64 -> expert_A[k][i]; 64..71 -> shared_A; else 0
// ---------------------------------------------------------------------------
__global__ __launch_bounds__(256) void prep_all(
    const float* __restrict__ x, const float* __restrict__ W,
    const float* __restrict__ expert_A, const float* __restrict__ shared_A,
    const float* __restrict__ expert_B, const float* __restrict__ shared_B,
    const float* __restrict__ collab,
    __bf16* __restrict__ xb, float* __restrict__ x_mean,
    __bf16* __restrict__ Wb, __bf16* __restrict__ caug, __bf16* __restrict__ Ab)
{
    const int bid = blockIdx.x;
    const int t = threadIdx.x;
    if (bid < 256) {
        const int dc = bid & 1, sc = (bid >> 1) & 31, b = bid >> 6;
        const int i = dc * 1024 + t * 4;
        size_t base = ((size_t)b * SEQ + (size_t)sc * 64) * DIN + i;
        float ax = 0.f, ay = 0.f, az = 0.f, aw = 0.f;
        for (int s = 0; s < 64; ++s) {
            float4 v = *(const float4*)&x[base + (size_t)s * DIN];
            ax += v.x; ay += v.y; az += v.z; aw += v.w;
            bf16x4 h = { (__bf16)v.x, (__bf16)v.y, (__bf16)v.z, (__bf16)v.w };
            *(bf16x4*)&xb[base + (size_t)s * DIN] = h;
        }
        atomicAdd(&x_mean[(size_t)b * DIN + i],     ax);
        atomicAdd(&x_mean[(size_t)b * DIN + i + 1], ay);
        atomicAdd(&x_mean[(size_t)b * DIN + i + 2], az);
        atomicAdd(&x_mean[(size_t)b * DIN + i + 3], aw);
    } else if (bid < 4352) {
        size_t idx = ((size_t)(bid - 256) * 256 + t) * 4;
        float4 v = *(const float4*)&W[idx];
        bf16x4 h = { (__bf16)v.x, (__bf16)v.y, (__bf16)v.z, (__bf16)v.w };
        *(bf16x4*)&Wb[idx] = h;
    } else if (bid < 5376) {
        int idx = (bid - 4352) * 256 + t;      // 2048*128
        int k = idx & 127, o = idx >> 7;
        float cw = 1.0f / (1.0f + expf(-collab[0]));
        float v = 0.f;
        if (k < 64)
            v = (1.0f - cw) * 2.0f * expert_B[((size_t)(k >> 3) * DOUT + o) * RANK + (k & 7)];
        else if (k < 72)
            v = cw * 2.0f * shared_B[(size_t)o * RANK + (k - 64)];
        caug[idx] = (__bf16)v;
    } else {
        int idx = (bid - 5376) * 256 + t;      // 128*2048: [k][i]
        int i = idx & 2047, k = idx >> 11;
        float v = 0.f;
        if (k < 64)      v = expert_A[(size_t)k * DIN + i];
        else if (k < 72) v = shared_A[(size_t)(k - 64) * DIN + i];
        Ab[idx] = (__bf16)v;
    }
}

// ---------------------------------------------------------------------------
// K2 (260 blocks): blocks [0,256): split-K low-rank GEMM
//   pt[kc][m][128] = bf16( xb[m][kc*512:+512] @ Ab[:, kc*512:+512]^T )
//   (kc = bid&3, m-tile = bid>>2; m97 structure, BK=32, no swizzle)
// blocks [256,260): routing softmax for batch b = bid-256 (hidden under gemm_t)
// ---------------------------------------------------------------------------
__global__ __launch_bounds__(256) void gemm_t_rout(
    const __bf16* __restrict__ xb, const __bf16* __restrict__ Ab,
    const float* __restrict__ x_mean, const float* __restrict__ task_emb,
    __bf16* __restrict__ pt, float* __restrict__ routing)
{
    __shared__ __bf16 lsA[128 * 32];
    __shared__ __bf16 lsB[128 * 32];
    __shared__ float red[256];
    __shared__ float logits[NEXP];
    const int bid = blockIdx.x;
    const int t = threadIdx.x;

    if (bid >= 256) {
        // --- routing softmax for batch b ---
        const int b = bid - 256;
        float le[NEXP] = {0.f,0.f,0.f,0.f,0.f,0.f,0.f,0.f};
        for (int j = 0; j < DIN / 256; ++j) {
            int i = t + j * 256;
            float xm = x_mean[(size_t)b * DIN + i] * (1.0f / (float)SEQ);
            #pragma unroll
            for (int e = 0; e < NEXP; ++e)
                le[e] += xm * task_emb[(size_t)e * DIN + i];
        }
        for (int e = 0; e < NEXP; ++e) {
            red[t] = le[e];
            __syncthreads();
            for (int s = 128; s > 0; s >>= 1) {
                if (t < s) red[t] += red[t + s];
                __syncthreads();
            }
            if (t == 0) logits[e] = red[0];
            __syncthreads();
        }
        if (t == 0) {
            float mx = logits[0];
            for (int e = 1; e < NEXP; ++e) mx = fmaxf(mx, logits[e]);
            float ex[NEXP], den = 0.f;
            for (int e = 0; e < NEXP; ++e) { ex[e] = expf(logits[e] - mx); den += ex[e]; }
            for (int e = 0; e < NEXP; ++e) routing[b * NEXP + e] = ex[e] / den;
        }
        return;
    }

    // --- split-K low-rank GEMM ---
    const int lane = t & 63;
    const int wm = (t >> 6) >> 1, wn = (t >> 6) & 1;
    const int kc = bid & 3;
    const int m0 = (bid >> 2) * 128;

    f32x4 acc[4][4];
    #pragma unroll
    for (int a = 0; a < 4; ++a)
        #pragma unroll
        for (int c = 0; c < 4; ++c) acc[a][c] = (f32x4){0.f, 0.f, 0.f, 0.f};

    for (int k0 = kc * 512; k0 < kc * 512 + 512; k0 += 32) {
        #pragma unroll
        for (int q = 0; q < 2; ++q) {
            int L = q * 256 + t;
            int row = L >> 2, seg = L & 3;
            const __bf16* gpA = xb + (size_t)(m0 + row) * DIN + k0 + seg * 8;
            const __bf16* gpB = Ab + (size_t)row * DIN + k0 + seg * 8;
            int Lu = q * 256 + (t & ~63);
            __builtin_amdgcn_global_load_lds((GLOBAL_AS void*)gpA,
                (LDS_AS void*)&lsA[Lu * 8], 16, 0, 0);
            __builtin_amdgcn_global_load_lds((GLOBAL_AS void*)gpB,
                (LDS_AS void*)&lsB[Lu * 8], 16, 0, 0);
        }
        __syncthreads();
        bf16x8 af[4], bfr[4];
        #pragma unroll
        for (int tm = 0; tm < 4; ++tm)
            af[tm]  = *(const bf16x8*)&lsA[(wm * 64 + tm * 16 + (lane & 15)) * 32 + (lane >> 4) * 8];
        #pragma unroll
        for (int tn = 0; tn < 4; ++tn)
            bfr[tn] = *(const bf16x8*)&lsB[(wn * 64 + tn * 16 + (lane & 15)) * 32 + (lane >> 4) * 8];
        #pragma unroll
        for (int tm = 0; tm < 4; ++tm)
            #pragma unroll
            for (int tn = 0; tn < 4; ++tn)
                acc[tm][tn] = __builtin_amdgcn_mfma_f32_16x16x32_bf16(
                    af[tm], bfr[tn], acc[tm][tn], 0, 0, 0);
        __syncthreads();
    }
    #pragma unroll
    for (int tm = 0; tm < 4; ++tm)
        #pragma unroll
        for (int tn = 0; tn < 4; ++tn) {
            int col = wn * 64 + tn * 16 + (lane & 15);
            #pragma unroll
            for (int v = 0; v < 4; ++v) {
                int row = m0 + wm * 64 + tm * 16 + (lane >> 4) * 4 + v;
                pt[((size_t)kc * MTOT + row) * KP + col] = (__bf16)acc[tm][tn][v];
            }
        }
}

// ---------------------------------------------------------------------------
// K3: tb[m][k] = bf16( routing_factor(b(m),k) * sum_kc pt[kc][m][k] )
//     factor = routing[b][k>>3] for k<64; 1.0 for 64..71; (pt is 0 beyond 72)
// ---------------------------------------------------------------------------
__global__ __launch_bounds__(256) void reduce_route(
    const __bf16* __restrict__ pt, const float* __restrict__ routing,
    __bf16* __restrict__ tb)
{
    size_t idx = ((size_t)blockIdx.x * 256 + threadIdx.x) * 4;  // over 8192*128
    int k0 = (int)(idx & 127);
    int m  = (int)(idx >> 7);
    int b  = m >> 11;
    float f = (k0 < 64) ? routing[b * NEXP + (k0 >> 3)] : 1.0f;
    float sx = 0.f, sy = 0.f, sz = 0.f, sw = 0.f;
    #pragma unroll
    for (int kc = 0; kc < 4; ++kc) {
        bf16x4 v = *(const bf16x4*)&pt[(size_t)kc * MTOT * KP + idx];
        sx += (float)v[0]; sy += (float)v[1]; sz += (float)v[2]; sw += (float)v[3];
    }
    bf16x4 h = { (__bf16)(sx * f), (__bf16)(sy * f), (__bf16)(sz * f), (__bf16)(sw * f) };
    *(bf16x4*)&tb[idx] = h;
}

// ---------------------------------------------------------------------------
// K4: out = xb @ Wb^T + tb @ caug^T + bias
// BK=64 (34 barriers vs 67), 8-slot XOR swizzle (required at stride 64),
// grid (x=64 m-tiles, y=16 n-tiles) so the 16 blocks sharing an A-tile get
// linear ids == x (mod 8) -> same XCD -> xb fetched once per XCD.
// ---------------------------------------------------------------------------
__global__ __launch_bounds__(256) void gemm_main(
    const __bf16* __restrict__ xb, const __bf16* __restrict__ Wb,
    const __bf16* __restrict__ tb, const __bf16* __restrict__ caug,
    const float* __restrict__ bias, float* __restrict__ out)
{
    __shared__ __bf16 lsA[128 * 64];
    __shared__ __bf16 lsB[128 * 64];
    const int t = threadIdx.x;
    const int lane = t & 63;
    const int wm = (t >> 6) >> 1, wn = (t >> 6) & 1;
    const int m0 = blockIdx.x * 128;
    const int n0 = blockIdx.y * 128;

    f32x4 acc[4][4];
    #pragma unroll
    for (int a = 0; a < 4; ++a)
        #pragma unroll
        for (int c = 0; c < 4; ++c) acc[a][c] = (f32x4){0.f, 0.f, 0.f, 0.f};

    auto kstep = [&](const __bf16* baseA, const __bf16* baseB,
                     int strideA, int strideB, int k0) {
        #pragma unroll
        for (int q = 0; q < 4; ++q) {
            int G = q * 256 + t;
            int row = G >> 3, sl = G & 7;
            int seg = sl ^ (row & 7);   // LDS slot sl of row holds global seg
            const __bf16* gpA = baseA + (size_t)row * strideA + k0 + seg * 8;
            const __bf16* gpB = baseB + (size_t)row * strideB + k0 + seg * 8;
            int Lu = (q * 256 + (t & ~63)) * 8;
            __builtin_amdgcn_global_load_lds((GLOBAL_AS void*)gpA,
                (LDS_AS void*)&lsA[Lu], 16, 0, 0);
            __builtin_amdgcn_global_load_lds((GLOBAL_AS void*)gpB,
                (LDS_AS void*)&lsB[Lu], 16, 0, 0);
        }
        __syncthreads();
        #pragma unroll
        for (int kk = 0; kk < 2; ++kk) {
            bf16x8 af[4], bfr[4];
            #pragma unroll
            for (int tm = 0; tm < 4; ++tm) {
                int r = wm * 64 + tm * 16 + (lane & 15);
                int slot = (kk * 4 + (lane >> 4)) ^ (r & 7);
                af[tm] = *(const bf16x8*)&lsA[r * 64 + slot * 8];
            }
            #pragma unroll
            for (int tn = 0; tn < 4; ++tn) {
                int r = wn * 64 + tn * 16 + (lane & 15);
                int slot = (kk * 4 + (lane >> 4)) ^ (r & 7);
                bfr[tn] = *(const bf16x8*)&lsB[r * 64 + slot * 8];
            }
            #pragma unroll
            for (int tm = 0; tm < 4; ++tm)
                #pragma unroll
                for (int tn = 0; tn < 4; ++tn)
                    acc[tm][tn] = __builtin_amdgcn_mfma_f32_16x16x32_bf16(
                        af[tm], bfr[tn], acc[tm][tn], 0, 0, 0);
        }
        __syncthreads();
    };

    // main: K = 2048 over (xb, Wb)
    for (int k0 = 0; k0 < DIN; k0 += 64)
        kstep(xb + (size_t)m0 * DIN, Wb + (size_t)n0 * DIN, DIN, DIN, k0);
    // correction: K = 128 (zeros beyond 72) over (tb, caug)
    for (int k0 = 0; k0 < KP; k0 += 64)
        kstep(tb + (size_t)m0 * KP, caug + (size_t)n0 * KP, KP, KP, k0);

    #pragma unroll
    for (int tm = 0; tm < 4; ++tm)
        #pragma unroll
        for (int tn = 0; tn < 4; ++tn) {
            int col = n0 + wn * 64 + tn * 16 + (lane & 15);
            float bv = bias[col];
            #pragma unroll
            for (int v = 0; v < 4; ++v) {
                int row = m0 + wm * 64 + tm * 16 + (lane >> 4) * 4 + v;
                out[(size_t)row * DOUT + col] = acc[tm][tn][v] + bv;
            }
        }
}

// ---------------------------------------------------------------------------
// Workspace (bytes):
//   xb      @ 0         : 33,554,432   (8192x2048 bf16)
//   Wb      @ 33554432  :  8,388,608   (2048x2048 bf16)
//   pt      @ 41943040  :  8,388,608   (4x8192x128 bf16)
//   tb      @ 50331648  :  2,097,152   (8192x128 bf16)
//   caug    @ 52428800  :    524,288   (2048x128 bf16)
//   Ab      @ 52953088  :    524,288   (128x2048 bf16)
//   x_mean  @ 53477376  :     32,768   (4x2048 f32)
//   routing @ 53510144  :        256
// ---------------------------------------------------------------------------
extern "C" void kernel_launch(void* const* d_in, const int* in_sizes, int n_in,
                              void* d_out, int out_size, void* d_ws, size_t ws_size,
                              hipStream_t stream)
{
    const float* x        = (const float*)d_in[0];
    const float* base_W   = (const float*)d_in[1];
    const float* base_b   = (const float*)d_in[2];
    const float* shared_A = (const float*)d_in[3];
    const float* shared_B = (const float*)d_in[4];
    const float* expert_A = (const float*)d_in[5];
    const float* expert_B = (const float*)d_in[6];
    const float* task_emb = (const float*)d_in[7];
    const float* collab_w = (const float*)d_in[8];
    float* out = (float*)d_out;

    char* ws = (char*)d_ws;
    __bf16* xb      = (__bf16*)(ws + 0);
    __bf16* Wb      = (__bf16*)(ws + 33554432);
    __bf16* pt      = (__bf16*)(ws + 41943040);
    __bf16* tb      = (__bf16*)(ws + 50331648);
    __bf16* caug    = (__bf16*)(ws + 52428800);
    __bf16* Ab      = (__bf16*)(ws + 52953088);
    float*  x_mean  = (float*) (ws + 53477376);
    float*  routing = (float*) (ws + 53510144);

    hipMemsetAsync(x_mean, 0, BATCH * DIN * sizeof(float), stream);
    prep_all    <<<dim3(6400), 256, 0, stream>>>(x, base_W, expert_A, shared_A,
                                                 expert_B, shared_B, collab_w,
                                                 xb, x_mean, Wb, caug, Ab);
    gemm_t_rout <<<dim3(260), 256, 0, stream>>>(xb, Ab, x_mean, task_emb, pt, routing);
    reduce_route<<<dim3(1024), 256, 0, stream>>>(pt, routing, tb);
    gemm_main   <<<dim3(64, 16), 256, 0, stream>>>(xb, Wb, tb, caug, base_b, out);
}